// Round 5
// baseline (226.665 us; speedup 1.0000x reference)
//
#include <hip/hip_runtime.h>

#define HW 3600
#define PADR 3712            // 29*128 padded rows
#define NF4 900
#define CAP 16384
#define KSEL 100
#define NT 58                // 64-col tiles
typedef unsigned long long U64;

using short8   = __attribute__((ext_vector_type(8))) short;
using float4v  = __attribute__((ext_vector_type(4))) float;
using float16v = __attribute__((ext_vector_type(16))) float;

__device__ __forceinline__ unsigned monof(float f) {
    unsigned b = __float_as_uint(f);
    return (b & 0x80000000u) ? ~b : (b | 0x80000000u);
}
__device__ __forceinline__ float unmonof(unsigned m) {
    return __uint_as_float((m & 0x80000000u) ? (m ^ 0x80000000u) : ~m);
}
__device__ __forceinline__ unsigned short f2bf(float f) {   // RNE
    unsigned b = __float_as_uint(f);
    return (unsigned short)((b + 0x7FFFu + ((b >> 16) & 1u)) >> 16);
}
__device__ __forceinline__ float bf2f(unsigned short h) {
    return __uint_as_float(((unsigned)h) << 16);
}
__device__ __forceinline__ void async16(const void* g, void* l) {
    __builtin_amdgcn_global_load_lds((const __attribute__((address_space(1))) void*)g,
                                     (__attribute__((address_space(3))) void*)l, 16, 0, 0);
}

// chunk-major element address (in shorts): buf[b][rblk][kb][row128][8]

// ---- Pass 0: convert x -> chunk-major split-bf16; zero den+cnt (no memset) -
__global__ __launch_bounds__(256) void conv_k(
    const float* __restrict__ x,
    unsigned short* __restrict__ hiT, unsigned short* __restrict__ loT,
    unsigned* __restrict__ zero_region)   // den(28800 f) ++ cnt(4) ++ tau(4)
{
    int b = blockIdx.z, l0 = blockIdx.x * 64, d0 = blockIdx.y * 64;
    __shared__ float t[64][65];
    int tid = threadIdx.x;
    if (blockIdx.y == 0 && blockIdx.z == 0) {
        int base = blockIdx.x * 512;
        for (int i = tid; i < 512; i += 256) {
            int g = base + i;
            if (g < 28808) zero_region[g] = 0u;
        }
    }
#pragma unroll
    for (int r = 0; r < 4; r++) {
        int idx = tid + 256 * r;              // 1024 float4 slots
        int d = idx >> 4, lq = idx & 15;
        int l = l0 + lq * 4;
        const float* src = x + ((size_t)b * 128 + d0 + d) * HW;
        float4 v;
        if (l + 3 < HW) v = *(const float4*)(src + l);
        else {
            v.x = (l     < HW) ? src[l]     : 0.f;
            v.y = (l + 1 < HW) ? src[l + 1] : 0.f;
            v.z = (l + 2 < HW) ? src[l + 2] : 0.f;
            v.w = (l + 3 < HW) ? src[l + 3] : 0.f;
        }
        t[lq * 4 + 0][d] = v.x; t[lq * 4 + 1][d] = v.y;
        t[lq * 4 + 2][d] = v.z; t[lq * 4 + 3][d] = v.w;
    }
    __syncthreads();
    const int rblk = l0 >> 7;
#pragma unroll
    for (int r = 0; r < 2; r++) {
        int idx = tid + 256 * r;              // 512 chunks of 8 bf16
        int l = idx & 63, dq = idx >> 6;      // row-inner -> coalesced stores
        unsigned hp[4], lp[4];
#pragma unroll
        for (int j = 0; j < 4; j++) {
            float f0 = t[l][dq * 8 + 2 * j], f1 = t[l][dq * 8 + 2 * j + 1];
            unsigned short h0 = f2bf(f0), h1 = f2bf(f1);
            unsigned short g0 = f2bf(f0 - bf2f(h0)), g1 = f2bf(f1 - bf2f(h1));
            hp[j] = (unsigned)h0 | ((unsigned)h1 << 16);
            lp[j] = (unsigned)g0 | ((unsigned)g1 << 16);
        }
        size_t o = ((size_t)(b * 29 + rblk) * 16 + (d0 >> 3) + dq) * 1024
                 + (size_t)((l0 + l) & 127) * 8;
        *(uint4*)(hiT + o) = make_uint4(hp[0], hp[1], hp[2], hp[3]);
        *(uint4*)(loT + o) = make_uint4(lp[0], lp[1], lp[2], lp[3]);
    }
}

// ---- Pass A: 512-thread 8-wave GEMM, DIRECT global->register operands ------
// R1-R4: four schedules of the LDS-staged loop all pinned at 76-78us across
// occupancy 20-54% -> limiter is the staging path itself (DMA + LDS port +
// vmcnt-coupled barrier each K-step). This version removes LDS/barriers from
// the K-loop: operand panels are L2-resident (~3.8MB/batch), fragments are
// coalesced 16B/lane loads from thread-constant bases + const offsets, 48
// loads : 48 MFMAs pure dataflow. m204 bijective XCD swizzle keeps each XCD
// sweeping bx fast at fixed (by,batch) so its B panel (1.8MB) stays L2-hot.
// Identical addresses + MFMA order as staged version -> bit-identical output.
__global__ __launch_bounds__(512, 4) void gemm_mfma_k(
    const unsigned short* __restrict__ hiT, const unsigned short* __restrict__ loT,
    float* __restrict__ den_row, float* __restrict__ den_col,
    float* __restrict__ maxvt)
{
    // m204 bijective XCD remap of the 3364-block grid
    const int nwg = 29 * 29 * 4, q = nwg >> 3, r = nwg & 7;   // 420, 4
    int orig = blockIdx.x + 29 * (blockIdx.y + 29 * blockIdx.z);
    int xcd = orig & 7, idx = orig >> 3;
    int wg = (xcd < r ? xcd * (q + 1) : r * (q + 1) + (xcd - r) * q) + idx;
    const int bx = wg % 29; int tmp = wg / 29;
    const int by = tmp % 29; const int batch = tmp / 29;

    __shared__ float T[8][1024];       // epilogue transpose scratch (32 KB)
    __shared__ float rsB[128];
    __shared__ float csB[128];
    __shared__ unsigned mxB[2][128];

    const int tid = threadIdx.x;
    const int lane = tid & 63, w = tid >> 6;          // 8 waves
    const int l31 = lane & 31, h = lane >> 5;
    const int rg = w >> 2, cg = w & 3;                // compute role

    if (tid < 128) { rsB[tid] = 0.f; csB[tid] = 0.f; }
    if (tid < 256) mxB[tid >> 7][tid & 127] = 0u;     // 0u < every monof(log) value

    const size_t cbaseA = ((size_t)(batch * 29 + by) * 16) * 1024;
    const size_t cbaseB = ((size_t)((batch + 4) * 29 + bx) * 16) * 1024;
    // thread-constant bases (h folded in); all 48 loads are base + const offset
    const unsigned short* Ah = hiT + cbaseA + (size_t)h * 1024 + (size_t)(rg * 64 + l31) * 8;
    const unsigned short* Al = loT + cbaseA + (size_t)h * 1024 + (size_t)(rg * 64 + l31) * 8;
    const unsigned short* Bh = hiT + cbaseB + (size_t)h * 1024 + (size_t)(cg * 32 + l31) * 8;
    const unsigned short* Bl = loT + cbaseB + (size_t)h * 1024 + (size_t)(cg * 32 + l31) * 8;

    float16v acc[2];
    acc[0] = (float16v)(0.f);
    acc[1] = (float16v)(0.f);

#pragma unroll
    for (int ks = 0; ks < 4; ks++) {
        short8 fah[2][2], fal[2][2], fbh[2], fbl[2];
#pragma unroll
        for (int j = 0; j < 2; j++) {
            const size_t off = (size_t)(ks * 4 + j * 2) * 1024;
            fah[j][0] = *(const short8*)(Ah + off);
            fah[j][1] = *(const short8*)(Ah + off + 256);   // +32 rows
            fal[j][0] = *(const short8*)(Al + off);
            fal[j][1] = *(const short8*)(Al + off + 256);
            fbh[j]    = *(const short8*)(Bh + off);
            fbl[j]    = *(const short8*)(Bl + off);
        }
#pragma unroll
        for (int j = 0; j < 2; j++) {
#pragma unroll
            for (int mt = 0; mt < 2; mt++) {
                acc[mt] = __builtin_amdgcn_mfma_f32_32x32x16_bf16(fah[j][mt], fbh[j], acc[mt], 0, 0, 0);
                acc[mt] = __builtin_amdgcn_mfma_f32_32x32x16_bf16(fah[j][mt], fbl[j], acc[mt], 0, 0, 0);
                acc[mt] = __builtin_amdgcn_mfma_f32_32x32x16_bf16(fal[j][mt], fbh[j], acc[mt], 0, 0, 0);
            }
        }
    }
    __syncthreads();   // rsB/csB/mxB init visible; T free

    // ---- fused epilogue: one swizzled transpose pass -> rowsum + rowmax ----
    // C/D: col = cg*32 + l31, row = rg*64 + mt*32 + (reg&3)+8*(reg>>2)+4*h
    const float scale = 0.078125f;   // 1/(128*0.1)
    float* Tw = &T[w][0];            // wave-private 32x32, XOR-swizzled
    const bool interior = (bx < 28) && (by < 28);
    const int col0 = bx * 128 + cg * 32 + l31;
    const bool cv = interior || (col0 < HW);
    float cs = 0.f;

#pragma unroll
    for (int mt = 0; mt < 2; mt++) {
#pragma unroll
        for (int reg = 0; reg < 16; reg++) {
            float v = acc[mt][reg] * scale;
            float e = cv ? __expf(v) : 0.f;
            int rloc = (reg & 3) + 8 * (reg >> 2) + 4 * h;
            bool rv = interior || (by * 128 + rg * 64 + mt * 32 + rloc < HW);
            if (rv) cs += e;
            Tw[rloc * 32 + (l31 ^ rloc)] = e;         // swizzled: addr = r*32 + (c^r)
        }
        __asm__ __volatile__("s_waitcnt lgkmcnt(0)" ::: "memory");
        {
            float ps = 0.f, pm = 0.f;
#pragma unroll
            for (int i = 0; i < 16; i++) {
                float tv_ = Tw[l31 * 32 + ((h * 16 + i) ^ l31)];
                ps += tv_;
                pm = fmaxf(pm, tv_);
            }
            ps += __shfl_xor(ps, 32);
            pm = fmaxf(pm, __shfl_xor(pm, 32));
            if (h == 0) {
                atomicAdd(&rsB[rg * 64 + mt * 32 + l31], ps);
                atomicMax(&mxB[cg >> 1][rg * 64 + mt * 32 + l31],
                          monof(__logf(pm)));        // max(v) = log(max(exp v))
            }
        }
        __asm__ __volatile__("s_waitcnt lgkmcnt(0)" ::: "memory");
    }
    // col sums: h pair covers complementary rows of the same column
    cs += __shfl_xor(cs, 32);
    if (h == 0) atomicAdd(&csB[cg * 32 + l31], cs);
    __syncthreads();

    if (tid < 128) {
        int l = by * 128 + tid;
        if (l < HW) atomicAdd(&den_row[(size_t)batch * HW + l], rsB[tid]);
        int s = bx * 128 + tid;
        if (s < HW) atomicAdd(&den_col[(size_t)batch * HW + s], csB[tid]);
    }
    if (tid < 256) {
        int tile = tid >> 7, row = tid & 127;
        int l = by * 128 + row;
        if (l < HW)
            maxvt[((size_t)batch * NT + bx * 2 + tile) * PADR + l] =
                unmonof(mxB[tile][row]);
    }
}

// ---- Pass B1: WIDE keylb: per-row champion-key lower bound -----------------
// keylb[j] = max_t (2*maxvt[t][j] - maxlnc[t]) - ln(den_row[j])
__global__ __launch_bounds__(256) void stat_k(
    const float* __restrict__ den_row, const float* __restrict__ den_col,
    const float* __restrict__ maxvt, float* __restrict__ keylb)
{
    const int b = blockIdx.z, tid = threadIdx.x;
    __shared__ float lncS[HW];
    __shared__ float mlsS[NT];
    for (int i = tid; i < HW; i += 256)
        lncS[i] = __logf(den_col[(size_t)b * HW + i]);
    __syncthreads();
    if (tid < NT) {
        float mx = -3.4e38f;
        int s0 = tid * 64, s1 = s0 + 64; if (s1 > HW) s1 = HW;
        for (int s = s0; s < s1; s++) mx = fmaxf(mx, lncS[s]);
        mlsS[tid] = (s0 < HW) ? mx : 1e30f;
    }
    __syncthreads();
    int j = blockIdx.x * 240 + tid;
    if (tid < 240 && j < HW) {
        const float* mvb = maxvt + (size_t)b * NT * PADR;
        float b0 = -3.4e38f, b1_ = -3.4e38f;
#pragma unroll 4
        for (int tt = 0; tt < 58; tt += 2) {
            b0  = fmaxf(b0,  2.0f * mvb[(size_t)tt * PADR + j]       - mlsS[tt]);
            b1_ = fmaxf(b1_, 2.0f * mvb[(size_t)(tt + 1) * PADR + j] - mlsS[tt + 1]);
        }
        keylb[(size_t)b * HW + j] = fmaxf(b0, b1_) - __logf(den_row[(size_t)b * HW + j]);
    }
}

// ---- Pass B2: exact 100th-largest keylb via 2-level hist + rank -> tau -----
__global__ __launch_bounds__(256) void tau_k(
    const float* __restrict__ keylb, float* __restrict__ tau)
{
    const int b = blockIdx.z, tid = threadIdx.x;
    __shared__ unsigned keyS[HW];
    __shared__ unsigned hist[4096];
    __shared__ unsigned hpc[256];
    __shared__ int b1S, c1S, b2S, lcnt;
    __shared__ unsigned bestS;
    __shared__ unsigned list[1024];

    for (int i = tid; i < 4096; i += 256) hist[i] = 0u;
    if (tid == 0) { lcnt = 0; bestS = 0u; }
    __syncthreads();
    for (int i = tid; i < HW; i += 256) {
        unsigned k = monof(keylb[(size_t)b * HW + i]);
        keyS[i] = k;
        atomicAdd(&hist[k >> 20], 1u);
    }
    __syncthreads();
    { unsigned s = 0; for (int j = 0; j < 16; j++) s += hist[tid * 16 + j]; hpc[tid] = s; }
    __syncthreads();
    if (tid == 0) {
        unsigned cum = 0; int cs_ = 255;
        for (; cs_ > 0; cs_--) { if (cum + hpc[cs_] >= (unsigned)KSEL) break; cum += hpc[cs_]; }
        int bb = cs_ * 16 + 15;
        for (; bb > cs_ * 16; bb--) { if (cum + hist[bb] >= (unsigned)KSEL) break; cum += hist[bb]; }
        b1S = bb; c1S = (int)cum;
    }
    __syncthreads();
    int b1 = b1S;
    for (int i = tid; i < 4096; i += 256) hist[i] = 0u;
    __syncthreads();
    for (int i = tid; i < HW; i += 256) {
        unsigned k = keyS[i];
        if ((int)(k >> 20) == b1) atomicAdd(&hist[(k >> 8) & 4095], 1u);
    }
    __syncthreads();
    { unsigned s = 0; for (int j = 0; j < 16; j++) s += hist[tid * 16 + j]; hpc[tid] = s; }
    __syncthreads();
    if (tid == 0) {
        unsigned cum = (unsigned)c1S; int cs_ = 255;
        for (; cs_ > 0; cs_--) { if (cum + hpc[cs_] >= (unsigned)KSEL) break; cum += hpc[cs_]; }
        int bb = cs_ * 16 + 15;
        for (; bb > cs_ * 16; bb--) { if (cum + hist[bb] >= (unsigned)KSEL) break; cum += hist[bb]; }
        b2S = bb;
    }
    __syncthreads();
    int b2 = b2S;
    for (int i = tid; i < HW; i += 256) {
        unsigned k = keyS[i]; int hb = (int)(k >> 20);
        if (hb > b1 || (hb == b1 && (int)((k >> 8) & 4095) >= b2)) {
            int p = atomicAdd(&lcnt, 1);
            if (p < 1024) list[p] = k;
        }
    }
    __syncthreads();
    int L = lcnt; if (L > 1024) L = 1024;
    for (int i = tid; i < L; i += 256) {
        unsigned e = list[i]; int c = 0;
        for (int j = 0; j < L; j++) c += (list[j] >= e) ? 1 : 0;
        if (c >= KSEL) atomicMax(&bestS, e);
    }
    __syncthreads();
    if (tid == 0) tau[b] = unmonof(bestS) - 3e-4f;   // slack: cross-kernel drift
}

// ---- Pass C: pairs + recompute + collect; B in LDS; row-split x4 -----------
__global__ __launch_bounds__(256) void recollect_k(
    const unsigned short* __restrict__ hiT, const unsigned short* __restrict__ loT,
    const float* __restrict__ den_row, const float* __restrict__ den_col,
    const float* __restrict__ maxvt, const float* __restrict__ tau,
    uint2* __restrict__ cand, int* __restrict__ cnt)
{
    const int t = blockIdx.x, batch = blockIdx.y & 3, s = blockIdx.y >> 2;
    const int r0 = s * 900;
    const int tid = threadIdx.x;
    __shared__ float lnrS[900];
    __shared__ float lncS[64];
    __shared__ int prS[1024];
    __shared__ int pcS;
    __shared__ float mnlS;
    __shared__ __align__(16) unsigned short bS[2][16][64][8];   // 32768 B

    const int lane = tid & 63, w = tid >> 6;
    const size_t bbase = (size_t)(batch + 4) * PADR * 128;

    // stage B panel: cols t*64..t*64+63, full K, hi+lo; per (buf,kb) slice is
    // 64 lanes x 16B contiguous -> linear into bS[buf][kb][lane][0..7].
    {
        const size_t sbase = bbase + (size_t)(t >> 1) * 16 * 1024
                           + (size_t)(t & 1) * 512 + (size_t)lane * 8;
#pragma unroll
        for (int sl = w; sl < 32; sl += 4) {
            const int buf = sl >> 4, kb = sl & 15;
            const unsigned short* g = (buf ? loT : hiT) + sbase + (size_t)kb * 1024;
            async16(g, &bS[buf][kb][0][0]);
        }
    }

    if (tid < 64) {
        int c = t * 64 + tid;
        float lc = (c < HW) ? __logf(den_col[(size_t)batch * HW + c]) : 1e30f;
        lncS[tid] = lc;
        float mn = lc;
#pragma unroll
        for (int off = 1; off < 64; off <<= 1) mn = fminf(mn, __shfl_xor(mn, off));
        if (tid == 0) mnlS = mn;
    }
    for (int r = tid; r < 900; r += 256)
        lnrS[r] = __logf(den_row[(size_t)batch * HW + r0 + r]);
    if (tid == 0) pcS = 0;
    __syncthreads();

    const float tv = tau[batch];
    const float tvm = tv - 3e-4f;
    const float mnl = mnlS;
    const float* mv = maxvt + ((size_t)batch * NT + t) * PADR;
    for (int r = tid; r < 900; r += 256) {
        int rr = r0 + r;
        float bnd = 2.0f * mv[rr] - lnrS[r] - mnl;
        if (bnd >= tvm) {
            int p = atomicAdd(&pcS, 1);
            if (p < 1024) prS[p] = rr;
        }
    }
    __syncthreads();   // also drains the async16 B-stage
    int pc = pcS; if (pc > 1024) pc = 1024;
    if (pc == 0) return;

    const int m = lane & 15, q = lane >> 4;
    const float scale = 0.078125f;
    const size_t abase = (size_t)batch * PADR * 128;

    for (int g = w; g * 16 < pc; g += 4) {
        int pi = g * 16 + m;
        int rowv = (pi < pc) ? prS[pi] : HW;       // pad rows are zeros
        float ldrv = (pi < pc) ? lnrS[rowv - r0] : 0.f;
        size_t arow = abase + ((size_t)(rowv >> 7) * 16) * 1024 + (size_t)(rowv & 127) * 8;

        float4v acc[4];
#pragma unroll
        for (int i = 0; i < 4; i++) acc[i] = (float4v){0.f, 0.f, 0.f, 0.f};
#pragma unroll
        for (int k0 = 0; k0 < 128; k0 += 32) {
            int kb = (k0 >> 3) + q;
            short8 ah = *(const short8*)(hiT + arow + (size_t)kb * 1024);
            short8 al = *(const short8*)(loT + arow + (size_t)kb * 1024);
#pragma unroll
            for (int nt = 0; nt < 4; nt++) {
                short8 bh = *(const short8*)&bS[0][kb][nt * 16 + m][0];
                short8 bl = *(const short8*)&bS[1][kb][nt * 16 + m][0];
                acc[nt] = __builtin_amdgcn_mfma_f32_16x16x32_bf16(ah, bh, acc[nt], 0, 0, 0);
                acc[nt] = __builtin_amdgcn_mfma_f32_16x16x32_bf16(ah, bl, acc[nt], 0, 0, 0);
                acc[nt] = __builtin_amdgcn_mfma_f32_16x16x32_bf16(al, bh, acc[nt], 0, 0, 0);
            }
        }
#pragma unroll
        for (int nt = 0; nt < 4; nt++) {
            int c = t * 64 + nt * 16 + m;
            if (c >= HW) continue;
            float ldc = lncS[nt * 16 + m];
#pragma unroll
            for (int r = 0; r < 4; r++) {
                int ri = q * 4 + r;
                if (g * 16 + ri >= pc) continue;
                int rowo = __shfl(rowv, ri);
                float ldro = __shfl(ldrv, ri);
                float v = acc[nt][r] * scale;
                float tt2 = 2.0f * v - ldro - ldc;
                if (tt2 >= tv) {
                    int p = atomicAdd(&cnt[batch], 1);
                    if (p < CAP)
                        cand[(size_t)batch * CAP + p] =
                            make_uint2(monof(tt2), (unsigned)(rowo * HW + c));
                }
            }
        }
    }
}

// ---- Pass D1: exact top-K selection ONCE per batch, RADIX (was O(M^2)) -----
// 2-level histogram on the 32-bit score finds the 100th-key threshold in
// O(M); full 64-bit rank (with ~idx tiebreak) only on the <=1024 boundary
// list. Provably identical topiS: every excluded entry is strictly below
// every listed entry in the compared prefix bits, and the list contains all
// entries of global rank < 100.
__global__ __launch_bounds__(1024) void select_k(
    const uint2* __restrict__ cand, const int* __restrict__ cnt,
    const float* __restrict__ W, const float* __restrict__ bias,
    float* __restrict__ cst, float* __restrict__ sxy)
{
    const int batch = blockIdx.x;
    const int tid = threadIdx.x;
    const uint2* cb = cand + (size_t)batch * CAP;
    __shared__ unsigned hist[4096];
    __shared__ unsigned hpc[256];
    __shared__ int b1S, c1S, b2S, lcnt;
    __shared__ U64 list[1024];
    __shared__ int topiS[KSEL];
    __shared__ float cqx[KSEL], cqy[KSEL], crx[KSEL], cry[KSEL];

    int M = cnt[batch]; if (M > CAP) M = CAP;
    for (int i = tid; i < 4096; i += 1024) hist[i] = 0u;
    if (tid == 0) lcnt = 0;
    __syncthreads();
    for (int i = tid; i < M; i += 1024) atomicAdd(&hist[cb[i].x >> 20], 1u);
    __syncthreads();
    if (tid < 256) { unsigned s = 0; for (int j = 0; j < 16; j++) s += hist[tid * 16 + j]; hpc[tid] = s; }
    __syncthreads();
    if (tid == 0) {
        unsigned cum = 0; int cs_ = 255;
        for (; cs_ > 0; cs_--) { if (cum + hpc[cs_] >= (unsigned)KSEL) break; cum += hpc[cs_]; }
        int bb = cs_ * 16 + 15;
        for (; bb > cs_ * 16; bb--) { if (cum + hist[bb] >= (unsigned)KSEL) break; cum += hist[bb]; }
        b1S = bb; c1S = (int)cum;
    }
    __syncthreads();
    const int b1 = b1S;
    for (int i = tid; i < 4096; i += 1024) hist[i] = 0u;
    __syncthreads();
    for (int i = tid; i < M; i += 1024) {
        unsigned x = cb[i].x;
        if ((int)(x >> 20) == b1) atomicAdd(&hist[(x >> 8) & 4095], 1u);
    }
    __syncthreads();
    if (tid < 256) { unsigned s = 0; for (int j = 0; j < 16; j++) s += hist[tid * 16 + j]; hpc[tid] = s; }
    __syncthreads();
    if (tid == 0) {
        unsigned cum = (unsigned)c1S; int cs_ = 255;
        for (; cs_ > 0; cs_--) { if (cum + hpc[cs_] >= (unsigned)KSEL) break; cum += hpc[cs_]; }
        int bb = cs_ * 16 + 15;
        for (; bb > cs_ * 16; bb--) { if (cum + hist[bb] >= (unsigned)KSEL) break; cum += hist[bb]; }
        b2S = bb;
    }
    __syncthreads();
    const int b2 = b2S;
    for (int i = tid; i < M; i += 1024) {
        uint2 e = cb[i];
        int hb = (int)(e.x >> 20);
        if (hb > b1 || (hb == b1 && (int)((e.x >> 8) & 4095) >= b2)) {
            int p = atomicAdd(&lcnt, 1);
            if (p < 1024) list[p] = ((U64)e.x << 32) | (unsigned)(~e.y);
        }
    }
    __syncthreads();
    int L = lcnt; if (L > 1024) L = 1024;
    for (int i = tid; i < L; i += 1024) {
        U64 e = list[i]; int r = 0;
        for (int j = 0; j < L; j++) r += (list[j] > e) ? 1 : 0;
        if (r < KSEL) topiS[r] = (int)(~(unsigned)(e & 0xffffffffu));
    }
    __syncthreads();
    if (tid < KSEL) {
        int idx = topiS[tid];
        int qq = idx / HW, rr = idx - qq * HW;
        cqx[tid] = (float)(qq % 60) / 60.0f;
        cqy[tid] = (float)(qq / 60) / 60.0f;
        crx[tid] = (float)(rr % 60) / 60.0f;
        cry[tid] = (float)(rr / 60) / 60.0f;
    }
    __syncthreads();
    if (tid < 256) {
        const int d = tid & 127, hf = tid >> 7;
        const float* wrow = W + d * 200;
        float sx = 0.f, sy = 0.f, c = 0.f;
#pragma unroll 4
        for (int k = 0; k < KSEL; k++) {
            float wx = wrow[2 * k], wy = wrow[2 * k + 1];
            sx += wx; sy += wy;
            float cx = hf ? crx[k] : cqx[k];
            float cy = hf ? cry[k] : cqy[k];
            c += cx * wx + cy * wy;
        }
        cst[(hf ? (batch + 4) : batch) * 128 + d] = bias[d] - c;
        if (batch == 0 && hf == 0) { sxy[d] = sx; sxy[128 + d] = sy; }
    }
}

// ---- Pass D2: pure streaming elementwise output ----------------------------
__global__ __launch_bounds__(256) void final_k(
    const float* __restrict__ x, const float* __restrict__ cst,
    const float* __restrict__ sxy, float* __restrict__ out)
{
    const int bd = blockIdx.x;
    const int d = bd & 127;
    const int tid = threadIdx.x;
    const float cstv = cst[bd];
    const float sx = sxy[d], sy = sxy[128 + d];
    const float4* xin = (const float4*)(x + (size_t)bd * HW);
    float4* o4 = (float4*)(out + (size_t)bd * HW);
    for (int f = tid; f < NF4; f += 256) {
        float4 v = xin[f];
        int p0 = f * 4;
        float gy = (float)(p0 / 60) / 60.0f;
        float gxb = (float)(p0 % 60);
        float add = cstv + gy * sy;
        v.x += add + ((gxb      ) / 60.0f) * sx;
        v.y += add + ((gxb + 1.f) / 60.0f) * sx;
        v.z += add + ((gxb + 2.f) / 60.0f) * sx;
        v.w += add + ((gxb + 3.f) / 60.0f) * sx;
        o4[f] = v;
    }
}

extern "C" void kernel_launch(void* const* d_in, const int* in_sizes, int n_in,
                              void* d_out, int out_size, void* d_ws, size_t ws_size,
                              hipStream_t stream)
{
    const float* x    = (const float*)d_in[0];
    const float* W    = (const float*)d_in[1];
    const float* bias = (const float*)d_in[2];
    float* out = (float*)d_out;

    char* ws = (char*)d_ws;
    float*    den_row = (float*)(ws + 0);          // 57600
    float*    den_col = (float*)(ws + 57600);      // -> 115200
    int*      cnt     = (int*)  (ws + 115200);     // 16
    float*    tau     = (float*)(ws + 115216);     // 16 -> 115232 (conv zeroes 0..115232)
    float*    keylb   = (float*)(ws + 115264);     // 57600 -> 172864
    float*    cst     = (float*)(ws + 115264);     // reuses keylb (dead after tau_k): 4096
    float*    sxy     = (float*)(ws + 119360);     // 1024 -> 120384 (inside keylb region)
    uint2*    cand    = (uint2*)(ws + 172864);     // 524288 -> 697152
    float*    maxvt   = (float*)(ws + 697152);     // 3444736 -> 4141888
    unsigned short* hiT = (unsigned short*)(ws + 4141888);   // 7602176 -> 11744064
    unsigned short* loT = (unsigned short*)(ws + 11744064);  // 7602176 -> 19346240

    conv_k     <<<dim3(58, 2, 8),  256, 0, stream>>>(x, hiT, loT, (unsigned*)ws);
    gemm_mfma_k<<<dim3(29, 29, 4), 512, 0, stream>>>(hiT, loT, den_row, den_col, maxvt);
    stat_k     <<<dim3(15, 1, 4),  256, 0, stream>>>(den_row, den_col, maxvt, keylb);
    tau_k      <<<dim3(1, 1, 4),   256, 0, stream>>>(keylb, tau);
    recollect_k<<<dim3(NT, 16),    256, 0, stream>>>(hiT, loT, den_row, den_col, maxvt, tau, cand, cnt);
    select_k   <<<dim3(4),         1024, 0, stream>>>(cand, cnt, W, bias, cst, sxy);
    final_k    <<<dim3(1024),      256, 0, stream>>>(x, cst, sxy, out);
}

// Round 6
// 221.396 us; speedup vs baseline: 1.0238x; 1.0238x over previous
//
#include <hip/hip_runtime.h>

#define HW 3600
#define PADR 3712            // 29*128 padded rows
#define NF4 900
#define CAP 16384
#define KSEL 100
#define NT 58                // 64-col tiles
typedef unsigned long long U64;

using short8   = __attribute__((ext_vector_type(8))) short;
using float4v  = __attribute__((ext_vector_type(4))) float;
using float16v = __attribute__((ext_vector_type(16))) float;

__device__ __forceinline__ unsigned monof(float f) {
    unsigned b = __float_as_uint(f);
    return (b & 0x80000000u) ? ~b : (b | 0x80000000u);
}
__device__ __forceinline__ float unmonof(unsigned m) {
    return __uint_as_float((m & 0x80000000u) ? (m ^ 0x80000000u) : ~m);
}
__device__ __forceinline__ unsigned short f2bf(float f) {   // RNE
    unsigned b = __float_as_uint(f);
    return (unsigned short)((b + 0x7FFFu + ((b >> 16) & 1u)) >> 16);
}
__device__ __forceinline__ float bf2f(unsigned short h) {
    return __uint_as_float(((unsigned)h) << 16);
}
__device__ __forceinline__ void async16(const void* g, void* l) {
    __builtin_amdgcn_global_load_lds((const __attribute__((address_space(1))) void*)g,
                                     (__attribute__((address_space(3))) void*)l, 16, 0, 0);
}

// chunk-major element address (in shorts): buf[b][rblk][kb][row128][8]

// ---- Pass 0: convert x -> chunk-major split-bf16; zero den+cnt (no memset) -
__global__ __launch_bounds__(256) void conv_k(
    const float* __restrict__ x,
    unsigned short* __restrict__ hiT, unsigned short* __restrict__ loT,
    unsigned* __restrict__ zero_region)   // den(28800 f) ++ cnt(4) ++ tau(4)
{
    int b = blockIdx.z, l0 = blockIdx.x * 64, d0 = blockIdx.y * 64;
    __shared__ float t[64][65];
    int tid = threadIdx.x;
    if (blockIdx.y == 0 && blockIdx.z == 0) {
        int base = blockIdx.x * 512;
        for (int i = tid; i < 512; i += 256) {
            int g = base + i;
            if (g < 28808) zero_region[g] = 0u;
        }
    }
#pragma unroll
    for (int r = 0; r < 4; r++) {
        int idx = tid + 256 * r;              // 1024 float4 slots
        int d = idx >> 4, lq = idx & 15;
        int l = l0 + lq * 4;
        const float* src = x + ((size_t)b * 128 + d0 + d) * HW;
        float4 v;
        if (l + 3 < HW) v = *(const float4*)(src + l);
        else {
            v.x = (l     < HW) ? src[l]     : 0.f;
            v.y = (l + 1 < HW) ? src[l + 1] : 0.f;
            v.z = (l + 2 < HW) ? src[l + 2] : 0.f;
            v.w = (l + 3 < HW) ? src[l + 3] : 0.f;
        }
        t[lq * 4 + 0][d] = v.x; t[lq * 4 + 1][d] = v.y;
        t[lq * 4 + 2][d] = v.z; t[lq * 4 + 3][d] = v.w;
    }
    __syncthreads();
    const int rblk = l0 >> 7;
#pragma unroll
    for (int r = 0; r < 2; r++) {
        int idx = tid + 256 * r;              // 512 chunks of 8 bf16
        int l = idx & 63, dq = idx >> 6;      // row-inner -> coalesced stores
        unsigned hp[4], lp[4];
#pragma unroll
        for (int j = 0; j < 4; j++) {
            float f0 = t[l][dq * 8 + 2 * j], f1 = t[l][dq * 8 + 2 * j + 1];
            unsigned short h0 = f2bf(f0), h1 = f2bf(f1);
            unsigned short g0 = f2bf(f0 - bf2f(h0)), g1 = f2bf(f1 - bf2f(h1));
            hp[j] = (unsigned)h0 | ((unsigned)h1 << 16);
            lp[j] = (unsigned)g0 | ((unsigned)g1 << 16);
        }
        size_t o = ((size_t)(b * 29 + rblk) * 16 + (d0 >> 3) + dq) * 1024
                 + (size_t)((l0 + l) & 127) * 8;
        *(uint4*)(hiT + o) = make_uint4(hp[0], hp[1], hp[2], hp[3]);
        *(uint4*)(loT + o) = make_uint4(lp[0], lp[1], lp[2], lp[3]);
    }
}

// ---- Pass A: 512-thread 8-wave GEMM, DIRECT global->register operands ------
// (R5 version, best measured: 74.6us, FETCH 11.5MB. UNCHANGED this round.)
__global__ __launch_bounds__(512, 4) void gemm_mfma_k(
    const unsigned short* __restrict__ hiT, const unsigned short* __restrict__ loT,
    float* __restrict__ den_row, float* __restrict__ den_col,
    float* __restrict__ maxvt)
{
    // m204 bijective XCD remap of the 3364-block grid
    const int nwg = 29 * 29 * 4, q = nwg >> 3, r = nwg & 7;   // 420, 4
    int orig = blockIdx.x + 29 * (blockIdx.y + 29 * blockIdx.z);
    int xcd = orig & 7, idx = orig >> 3;
    int wg = (xcd < r ? xcd * (q + 1) : r * (q + 1) + (xcd - r) * q) + idx;
    const int bx = wg % 29; int tmp = wg / 29;
    const int by = tmp % 29; const int batch = tmp / 29;

    __shared__ float T[8][1024];       // epilogue transpose scratch (32 KB)
    __shared__ float rsB[128];
    __shared__ float csB[128];
    __shared__ unsigned mxB[2][128];

    const int tid = threadIdx.x;
    const int lane = tid & 63, w = tid >> 6;          // 8 waves
    const int l31 = lane & 31, h = lane >> 5;
    const int rg = w >> 2, cg = w & 3;                // compute role

    if (tid < 128) { rsB[tid] = 0.f; csB[tid] = 0.f; }
    if (tid < 256) mxB[tid >> 7][tid & 127] = 0u;     // 0u < every monof(log) value

    const size_t cbaseA = ((size_t)(batch * 29 + by) * 16) * 1024;
    const size_t cbaseB = ((size_t)((batch + 4) * 29 + bx) * 16) * 1024;
    // thread-constant bases (h folded in); all 48 loads are base + const offset
    const unsigned short* Ah = hiT + cbaseA + (size_t)h * 1024 + (size_t)(rg * 64 + l31) * 8;
    const unsigned short* Al = loT + cbaseA + (size_t)h * 1024 + (size_t)(rg * 64 + l31) * 8;
    const unsigned short* Bh = hiT + cbaseB + (size_t)h * 1024 + (size_t)(cg * 32 + l31) * 8;
    const unsigned short* Bl = loT + cbaseB + (size_t)h * 1024 + (size_t)(cg * 32 + l31) * 8;

    float16v acc[2];
    acc[0] = (float16v)(0.f);
    acc[1] = (float16v)(0.f);

#pragma unroll
    for (int ks = 0; ks < 4; ks++) {
        short8 fah[2][2], fal[2][2], fbh[2], fbl[2];
#pragma unroll
        for (int j = 0; j < 2; j++) {
            const size_t off = (size_t)(ks * 4 + j * 2) * 1024;
            fah[j][0] = *(const short8*)(Ah + off);
            fah[j][1] = *(const short8*)(Ah + off + 256);   // +32 rows
            fal[j][0] = *(const short8*)(Al + off);
            fal[j][1] = *(const short8*)(Al + off + 256);
            fbh[j]    = *(const short8*)(Bh + off);
            fbl[j]    = *(const short8*)(Bl + off);
        }
#pragma unroll
        for (int j = 0; j < 2; j++) {
#pragma unroll
            for (int mt = 0; mt < 2; mt++) {
                acc[mt] = __builtin_amdgcn_mfma_f32_32x32x16_bf16(fah[j][mt], fbh[j], acc[mt], 0, 0, 0);
                acc[mt] = __builtin_amdgcn_mfma_f32_32x32x16_bf16(fah[j][mt], fbl[j], acc[mt], 0, 0, 0);
                acc[mt] = __builtin_amdgcn_mfma_f32_32x32x16_bf16(fal[j][mt], fbh[j], acc[mt], 0, 0, 0);
            }
        }
    }
    __syncthreads();   // rsB/csB/mxB init visible; T free

    // ---- fused epilogue: one swizzled transpose pass -> rowsum + rowmax ----
    // C/D: col = cg*32 + l31, row = rg*64 + mt*32 + (reg&3)+8*(reg>>2)+4*h
    const float scale = 0.078125f;   // 1/(128*0.1)
    float* Tw = &T[w][0];            // wave-private 32x32, XOR-swizzled
    const bool interior = (bx < 28) && (by < 28);
    const int col0 = bx * 128 + cg * 32 + l31;
    const bool cv = interior || (col0 < HW);
    float cs = 0.f;

#pragma unroll
    for (int mt = 0; mt < 2; mt++) {
#pragma unroll
        for (int reg = 0; reg < 16; reg++) {
            float v = acc[mt][reg] * scale;
            float e = cv ? __expf(v) : 0.f;
            int rloc = (reg & 3) + 8 * (reg >> 2) + 4 * h;
            bool rv = interior || (by * 128 + rg * 64 + mt * 32 + rloc < HW);
            if (rv) cs += e;
            Tw[rloc * 32 + (l31 ^ rloc)] = e;         // swizzled: addr = r*32 + (c^r)
        }
        __asm__ __volatile__("s_waitcnt lgkmcnt(0)" ::: "memory");
        {
            float ps = 0.f, pm = 0.f;
#pragma unroll
            for (int i = 0; i < 16; i++) {
                float tv_ = Tw[l31 * 32 + ((h * 16 + i) ^ l31)];
                ps += tv_;
                pm = fmaxf(pm, tv_);
            }
            ps += __shfl_xor(ps, 32);
            pm = fmaxf(pm, __shfl_xor(pm, 32));
            if (h == 0) {
                atomicAdd(&rsB[rg * 64 + mt * 32 + l31], ps);
                atomicMax(&mxB[cg >> 1][rg * 64 + mt * 32 + l31],
                          monof(__logf(pm)));        // max(v) = log(max(exp v))
            }
        }
        __asm__ __volatile__("s_waitcnt lgkmcnt(0)" ::: "memory");
    }
    // col sums: h pair covers complementary rows of the same column
    cs += __shfl_xor(cs, 32);
    if (h == 0) atomicAdd(&csB[cg * 32 + l31], cs);
    __syncthreads();

    if (tid < 128) {
        int l = by * 128 + tid;
        if (l < HW) atomicAdd(&den_row[(size_t)batch * HW + l], rsB[tid]);
        int s = bx * 128 + tid;
        if (s < HW) atomicAdd(&den_col[(size_t)batch * HW + s], csB[tid]);
    }
    if (tid < 256) {
        int tile = tid >> 7, row = tid & 127;
        int l = by * 128 + row;
        if (l < HW)
            maxvt[((size_t)batch * NT + bx * 2 + tile) * PADR + l] =
                unmonof(mxB[tile][row]);
    }
}

// ---- Pass B: FUSED stat+tau (was 2 kernels + a keylb global round-trip) ----
// Per batch-block (grid 4 x 1024 thr): lnc, per-tile maxes, keylb ALL IN LDS,
// then 2-level histogram + boundary rank -> tau. Same float ops in the same
// order as the old stat_k/tau_k pair -> bit-identical tau.
__global__ __launch_bounds__(1024) void stattau_k(
    const float* __restrict__ den_row, const float* __restrict__ den_col,
    const float* __restrict__ maxvt, float* __restrict__ tau)
{
    const int b = blockIdx.x, tid = threadIdx.x;
    __shared__ float lncS[HW];
    __shared__ float mlsS[NT];
    __shared__ unsigned keyS[HW];
    __shared__ unsigned hist[4096];
    __shared__ unsigned hpc[256];
    __shared__ int b1S, c1S, b2S, lcnt;
    __shared__ unsigned bestS;
    __shared__ unsigned list[1024];

    for (int i = tid; i < HW; i += 1024)
        lncS[i] = __logf(den_col[(size_t)b * HW + i]);
    for (int i = tid; i < 4096; i += 1024) hist[i] = 0u;
    if (tid == 0) { lcnt = 0; bestS = 0u; }
    __syncthreads();
    if (tid < NT) {
        float mx = -3.4e38f;
        int s0 = tid * 64, s1 = s0 + 64; if (s1 > HW) s1 = HW;
        for (int s = s0; s < s1; s++) mx = fmaxf(mx, lncS[s]);
        mlsS[tid] = (s0 < HW) ? mx : 1e30f;
    }
    __syncthreads();
    // keylb -> keyS (in LDS) + first-level histogram
    {
        const float* mvb = maxvt + (size_t)b * NT * PADR;
        for (int j = tid; j < HW; j += 1024) {
            float b0 = -3.4e38f, b1_ = -3.4e38f;
#pragma unroll 4
            for (int tt = 0; tt < 58; tt += 2) {
                b0  = fmaxf(b0,  2.0f * mvb[(size_t)tt * PADR + j]       - mlsS[tt]);
                b1_ = fmaxf(b1_, 2.0f * mvb[(size_t)(tt + 1) * PADR + j] - mlsS[tt + 1]);
            }
            unsigned k = monof(fmaxf(b0, b1_) - __logf(den_row[(size_t)b * HW + j]));
            keyS[j] = k;
            atomicAdd(&hist[k >> 20], 1u);
        }
    }
    __syncthreads();
    if (tid < 256) { unsigned s = 0; for (int j = 0; j < 16; j++) s += hist[tid * 16 + j]; hpc[tid] = s; }
    __syncthreads();
    if (tid == 0) {
        unsigned cum = 0; int cs_ = 255;
        for (; cs_ > 0; cs_--) { if (cum + hpc[cs_] >= (unsigned)KSEL) break; cum += hpc[cs_]; }
        int bb = cs_ * 16 + 15;
        for (; bb > cs_ * 16; bb--) { if (cum + hist[bb] >= (unsigned)KSEL) break; cum += hist[bb]; }
        b1S = bb; c1S = (int)cum;
    }
    __syncthreads();
    int b1 = b1S;
    for (int i = tid; i < 4096; i += 1024) hist[i] = 0u;
    __syncthreads();
    for (int i = tid; i < HW; i += 1024) {
        unsigned k = keyS[i];
        if ((int)(k >> 20) == b1) atomicAdd(&hist[(k >> 8) & 4095], 1u);
    }
    __syncthreads();
    if (tid < 256) { unsigned s = 0; for (int j = 0; j < 16; j++) s += hist[tid * 16 + j]; hpc[tid] = s; }
    __syncthreads();
    if (tid == 0) {
        unsigned cum = (unsigned)c1S; int cs_ = 255;
        for (; cs_ > 0; cs_--) { if (cum + hpc[cs_] >= (unsigned)KSEL) break; cum += hpc[cs_]; }
        int bb = cs_ * 16 + 15;
        for (; bb > cs_ * 16; bb--) { if (cum + hist[bb] >= (unsigned)KSEL) break; cum += hist[bb]; }
        b2S = bb;
    }
    __syncthreads();
    int b2 = b2S;
    for (int i = tid; i < HW; i += 1024) {
        unsigned k = keyS[i]; int hb = (int)(k >> 20);
        if (hb > b1 || (hb == b1 && (int)((k >> 8) & 4095) >= b2)) {
            int p = atomicAdd(&lcnt, 1);
            if (p < 1024) list[p] = k;
        }
    }
    __syncthreads();
    int L = lcnt; if (L > 1024) L = 1024;
    for (int i = tid; i < L; i += 1024) {
        unsigned e = list[i]; int c = 0;
        for (int j = 0; j < L; j++) c += (list[j] >= e) ? 1 : 0;
        if (c >= KSEL) atomicMax(&bestS, e);
    }
    __syncthreads();
    if (tid == 0) tau[b] = unmonof(bestS) - 3e-4f;   // slack: cross-kernel drift
}

// ---- Pass C: pairs + recompute + collect; B in LDS; row-split x4 -----------
__global__ __launch_bounds__(256) void recollect_k(
    const unsigned short* __restrict__ hiT, const unsigned short* __restrict__ loT,
    const float* __restrict__ den_row, const float* __restrict__ den_col,
    const float* __restrict__ maxvt, const float* __restrict__ tau,
    uint2* __restrict__ cand, int* __restrict__ cnt)
{
    const int t = blockIdx.x, batch = blockIdx.y & 3, s = blockIdx.y >> 2;
    const int r0 = s * 900;
    const int tid = threadIdx.x;
    __shared__ float lnrS[900];
    __shared__ float lncS[64];
    __shared__ int prS[1024];
    __shared__ int pcS;
    __shared__ float mnlS;
    __shared__ __align__(16) unsigned short bS[2][16][64][8];   // 32768 B

    const int lane = tid & 63, w = tid >> 6;
    const size_t bbase = (size_t)(batch + 4) * PADR * 128;

    // stage B panel: cols t*64..t*64+63, full K, hi+lo; per (buf,kb) slice is
    // 64 lanes x 16B contiguous -> linear into bS[buf][kb][lane][0..7].
    {
        const size_t sbase = bbase + (size_t)(t >> 1) * 16 * 1024
                           + (size_t)(t & 1) * 512 + (size_t)lane * 8;
#pragma unroll
        for (int sl = w; sl < 32; sl += 4) {
            const int buf = sl >> 4, kb = sl & 15;
            const unsigned short* g = (buf ? loT : hiT) + sbase + (size_t)kb * 1024;
            async16(g, &bS[buf][kb][0][0]);
        }
    }

    if (tid < 64) {
        int c = t * 64 + tid;
        float lc = (c < HW) ? __logf(den_col[(size_t)batch * HW + c]) : 1e30f;
        lncS[tid] = lc;
        float mn = lc;
#pragma unroll
        for (int off = 1; off < 64; off <<= 1) mn = fminf(mn, __shfl_xor(mn, off));
        if (tid == 0) mnlS = mn;
    }
    for (int r = tid; r < 900; r += 256)
        lnrS[r] = __logf(den_row[(size_t)batch * HW + r0 + r]);
    if (tid == 0) pcS = 0;
    __syncthreads();

    const float tv = tau[batch];
    const float tvm = tv - 3e-4f;
    const float mnl = mnlS;
    const float* mv = maxvt + ((size_t)batch * NT + t) * PADR;
    for (int r = tid; r < 900; r += 256) {
        int rr = r0 + r;
        float bnd = 2.0f * mv[rr] - lnrS[r] - mnl;
        if (bnd >= tvm) {
            int p = atomicAdd(&pcS, 1);
            if (p < 1024) prS[p] = rr;
        }
    }
    __syncthreads();   // also drains the async16 B-stage
    int pc = pcS; if (pc > 1024) pc = 1024;
    if (pc == 0) return;

    const int m = lane & 15, q = lane >> 4;
    const float scale = 0.078125f;
    const size_t abase = (size_t)batch * PADR * 128;

    for (int g = w; g * 16 < pc; g += 4) {
        int pi = g * 16 + m;
        int rowv = (pi < pc) ? prS[pi] : HW;       // pad rows are zeros
        float ldrv = (pi < pc) ? lnrS[rowv - r0] : 0.f;
        size_t arow = abase + ((size_t)(rowv >> 7) * 16) * 1024 + (size_t)(rowv & 127) * 8;

        float4v acc[4];
#pragma unroll
        for (int i = 0; i < 4; i++) acc[i] = (float4v){0.f, 0.f, 0.f, 0.f};
#pragma unroll
        for (int k0 = 0; k0 < 128; k0 += 32) {
            int kb = (k0 >> 3) + q;
            short8 ah = *(const short8*)(hiT + arow + (size_t)kb * 1024);
            short8 al = *(const short8*)(loT + arow + (size_t)kb * 1024);
#pragma unroll
            for (int nt = 0; nt < 4; nt++) {
                short8 bh = *(const short8*)&bS[0][kb][nt * 16 + m][0];
                short8 bl = *(const short8*)&bS[1][kb][nt * 16 + m][0];
                acc[nt] = __builtin_amdgcn_mfma_f32_16x16x32_bf16(ah, bh, acc[nt], 0, 0, 0);
                acc[nt] = __builtin_amdgcn_mfma_f32_16x16x32_bf16(ah, bl, acc[nt], 0, 0, 0);
                acc[nt] = __builtin_amdgcn_mfma_f32_16x16x32_bf16(al, bh, acc[nt], 0, 0, 0);
            }
        }
#pragma unroll
        for (int nt = 0; nt < 4; nt++) {
            int c = t * 64 + nt * 16 + m;
            if (c >= HW) continue;
            float ldc = lncS[nt * 16 + m];
#pragma unroll
            for (int r = 0; r < 4; r++) {
                int ri = q * 4 + r;
                if (g * 16 + ri >= pc) continue;
                int rowo = __shfl(rowv, ri);
                float ldro = __shfl(ldrv, ri);
                float v = acc[nt][r] * scale;
                float tt2 = 2.0f * v - ldro - ldc;
                if (tt2 >= tv) {
                    int p = atomicAdd(&cnt[batch], 1);
                    if (p < CAP)
                        cand[(size_t)batch * CAP + p] =
                            make_uint2(monof(tt2), (unsigned)(rowo * HW + c));
                }
            }
        }
    }
}

// ---- Pass D: fused radix top-K select + elementwise output (was 2 kernels) -
// R0 measured: selection duplicated per-block was FASTER overall than a
// separate select kernel (launch overhead). Radix select makes the duplicate
// strictly cheaper than R0's O(M^2) rank. Identical top-K (64-bit key with
// ~idx tiebreak; boundary list contains every entry of global rank < 100).
__global__ __launch_bounds__(256) void final_k(
    const float* __restrict__ x, const float* __restrict__ W,
    const float* __restrict__ bias,
    const uint2* __restrict__ cand, const int* __restrict__ cnt,
    float* __restrict__ out)
{
    const int bd = blockIdx.x;
    const int b8 = bd >> 7, d = bd & 127;
    const int batch = b8 & 3;
    const bool useQ = (b8 < 4);
    const int tid = threadIdx.x;
    const int lane = tid & 63, w = tid >> 6;
    const uint2* cb = cand + (size_t)batch * CAP;

    __shared__ unsigned hist[4096];
    __shared__ unsigned hpc[256];
    __shared__ int b1S, c1S, b2S, lcnt;
    __shared__ U64 list[1024];
    __shared__ int topiS[KSEL];
    __shared__ float cxS[KSEL], cyS[KSEL];
    __shared__ float redC[4], redX[4], redY[4];
    __shared__ float cstS, sxS, syS;

    int M = cnt[batch]; if (M > CAP) M = CAP;
    for (int i = tid; i < 4096; i += 256) hist[i] = 0u;
    if (tid == 0) lcnt = 0;
    __syncthreads();
    for (int i = tid; i < M; i += 256) atomicAdd(&hist[cb[i].x >> 20], 1u);
    __syncthreads();
    { unsigned s = 0; for (int j = 0; j < 16; j++) s += hist[tid * 16 + j]; hpc[tid] = s; }
    __syncthreads();
    if (tid == 0) {
        unsigned cum = 0; int cs_ = 255;
        for (; cs_ > 0; cs_--) { if (cum + hpc[cs_] >= (unsigned)KSEL) break; cum += hpc[cs_]; }
        int bb = cs_ * 16 + 15;
        for (; bb > cs_ * 16; bb--) { if (cum + hist[bb] >= (unsigned)KSEL) break; cum += hist[bb]; }
        b1S = bb; c1S = (int)cum;
    }
    __syncthreads();
    const int b1 = b1S;
    for (int i = tid; i < 4096; i += 256) hist[i] = 0u;
    __syncthreads();
    for (int i = tid; i < M; i += 256) {
        unsigned xk = cb[i].x;
        if ((int)(xk >> 20) == b1) atomicAdd(&hist[(xk >> 8) & 4095], 1u);
    }
    __syncthreads();
    { unsigned s = 0; for (int j = 0; j < 16; j++) s += hist[tid * 16 + j]; hpc[tid] = s; }
    __syncthreads();
    if (tid == 0) {
        unsigned cum = (unsigned)c1S; int cs_ = 255;
        for (; cs_ > 0; cs_--) { if (cum + hpc[cs_] >= (unsigned)KSEL) break; cum += hpc[cs_]; }
        int bb = cs_ * 16 + 15;
        for (; bb > cs_ * 16; bb--) { if (cum + hist[bb] >= (unsigned)KSEL) break; cum += hist[bb]; }
        b2S = bb;
    }
    __syncthreads();
    const int b2 = b2S;
    for (int i = tid; i < M; i += 256) {
        uint2 e = cb[i];
        int hb = (int)(e.x >> 20);
        if (hb > b1 || (hb == b1 && (int)((e.x >> 8) & 4095) >= b2)) {
            int p = atomicAdd(&lcnt, 1);
            if (p < 1024) list[p] = ((U64)e.x << 32) | (unsigned)(~e.y);
        }
    }
    __syncthreads();
    int L = lcnt; if (L > 1024) L = 1024;
    for (int i = tid; i < L; i += 256) {
        U64 e = list[i]; int r = 0;
        for (int j = 0; j < L; j++) r += (list[j] > e) ? 1 : 0;
        if (r < KSEL) topiS[r] = (int)(~(unsigned)(e & 0xffffffffu));
    }
    __syncthreads();
    if (tid < KSEL) {
        int idx = topiS[tid];
        int qq = idx / HW, rr = idx - qq * HW;
        int sel = useQ ? qq : rr;
        cxS[tid] = (float)(sel % 60) / 60.0f;
        cyS[tid] = (float)(sel / 60) / 60.0f;
    }
    __syncthreads();
    float pC = 0.f, pX = 0.f, pY = 0.f;
    if (tid < KSEL) {
        float wx = W[d * 200 + 2 * tid], wy = W[d * 200 + 2 * tid + 1];
        pC = cxS[tid] * wx + cyS[tid] * wy;
        pX = wx; pY = wy;
    }
#pragma unroll
    for (int off = 1; off < 64; off <<= 1) {
        pC += __shfl_xor(pC, off);
        pX += __shfl_xor(pX, off);
        pY += __shfl_xor(pY, off);
    }
    if (lane == 0) { redC[w] = pC; redX[w] = pX; redY[w] = pY; }
    __syncthreads();
    if (tid == 0) {
        cstS = bias[d] - (redC[0] + redC[1] + redC[2] + redC[3]);
        sxS  = redX[0] + redX[1] + redX[2] + redX[3];
        syS  = redY[0] + redY[1] + redY[2] + redY[3];
    }
    __syncthreads();
    const float cst = cstS, sx = sxS, sy = syS;
    const float4* xin = (const float4*)(x + (size_t)bd * HW);
    float4* o4 = (float4*)(out + (size_t)bd * HW);
    for (int f = tid; f < NF4; f += 256) {
        float4 v = xin[f];
        int p0 = f * 4;
        float gy = (float)(p0 / 60) / 60.0f;
        float gxb = (float)(p0 % 60);
        float add = cst + gy * sy;
        v.x += add + ((gxb       ) / 60.0f) * sx;
        v.y += add + ((gxb + 1.f) / 60.0f) * sx;
        v.z += add + ((gxb + 2.f) / 60.0f) * sx;
        v.w += add + ((gxb + 3.f) / 60.0f) * sx;
        o4[f] = v;
    }
}

extern "C" void kernel_launch(void* const* d_in, const int* in_sizes, int n_in,
                              void* d_out, int out_size, void* d_ws, size_t ws_size,
                              hipStream_t stream)
{
    const float* x    = (const float*)d_in[0];
    const float* W    = (const float*)d_in[1];
    const float* bias = (const float*)d_in[2];
    float* out = (float*)d_out;

    char* ws = (char*)d_ws;
    float*    den_row = (float*)(ws + 0);          // 57600
    float*    den_col = (float*)(ws + 57600);      // -> 115200
    int*      cnt     = (int*)  (ws + 115200);     // 16
    float*    tau     = (float*)(ws + 115216);     // 16 -> 115232 (conv zeroes 0..115232)
    uint2*    cand    = (uint2*)(ws + 172864);     // 524288 -> 697152
    float*    maxvt   = (float*)(ws + 697152);     // 3444736 -> 4141888
    unsigned short* hiT = (unsigned short*)(ws + 4141888);   // 7602176 -> 11744064
    unsigned short* loT = (unsigned short*)(ws + 11744064);  // 7602176 -> 19346240

    conv_k     <<<dim3(58, 2, 8),  256,  0, stream>>>(x, hiT, loT, (unsigned*)ws);
    gemm_mfma_k<<<dim3(29, 29, 4), 512,  0, stream>>>(hiT, loT, den_row, den_col, maxvt);
    stattau_k  <<<dim3(4),         1024, 0, stream>>>(den_row, den_col, maxvt, tau);
    recollect_k<<<dim3(NT, 16),    256,  0, stream>>>(hiT, loT, den_row, den_col, maxvt, tau, cand, cnt);
    final_k    <<<dim3(1024),      256,  0, stream>>>(x, W, bias, cand, cnt, out);
}